// Round 5
// baseline (3015.427 us; speedup 1.0000x reference)
//
#include <hip/hip_runtime.h>
#include <math.h>

#define NB 16        // batch
#define NT 256       // threads per workgroup
#define NWG 256      // workgroups for wide phases
#define TT 32        // timesteps
#define INP 256
#define HH 512
#define RH 4
#define CWID 64
#define MM 512
#define IFACE 471
#define DELTA 1e-6f
#define AP 516       // padded LDS row stride (fp32) for 512-wide tiles

#define NTLOAD(p_) __builtin_nontemporal_load(p_)

// ---------------- persistent device state (avoids ws_size assumptions) -------
__device__ __align__(16) float g_h[2][NB][HH];   // double-buffered across phase1
__device__ __align__(16) float g_c[NB][HH];
__device__ __align__(16) float g_lr[NB][INP];
__device__ __align__(16) float g_usage[NB][MM];
__device__ __align__(16) float g_ww[NB][MM];
__device__ __align__(16) float g_prec[2][NB][MM]; // double-buffered: L-update needs OLD prec
__device__ __align__(16) float g_rw[NB][RH][MM];
__device__ __align__(16) float g_mem[NB][MM][CWID];
__device__ __align__(16) float g_L[NB][MM][MM];   // 16.8 MB, partitioned (b, 32-row slice)
__device__ __align__(16) float g_out[NB][HH];
__device__ __align__(16) float g_xi[NB][HH];
__device__ __align__(16) float g_rkn[NB][RH][CWID]; // normalized read keys
__device__ __align__(16) float g_rs[NB][RH];
__device__ __align__(16) float g_erase[NB][CWID];
__device__ __align__(16) float g_wv[NB][CWID];
__device__ __align__(16) float g_modes[NB][RH][3];
__device__ __align__(16) float g_fwd[NB][RH][MM];
__device__ __align__(16) float g_bwdp[NB][16][RH][MM]; // bwd partials per row-slice
__device__ __align__(16) float g_e[NB][RH][MM];        // unnormalized read-content exp
__device__ __align__(16) float g_cwsp[NB][16][RH];     // partial sums of g_e

struct P {
  const float *x, *W_ih, *b_ih, *W_hh, *b_hh, *W_out, *b_out, *W_int, *b_int, *W_mem, *b_mem;
  float* y;
};

__device__ __forceinline__ float sigf(float x)  { return 1.f / (1.f + __expf(-x)); }
__device__ __forceinline__ float splus(float x) { return fmaxf(x, 0.f) + log1pf(__expf(-fabsf(x))); }

__device__ __forceinline__ void zfill(float* a, long n) {
  const long stride = (long)gridDim.x * blockDim.x;
  for (long i = (long)blockIdx.x * blockDim.x + threadIdx.x; i < n; i += stride) a[i] = 0.f;
}

// ---------------- init: deterministic re-zero of all carried state ----------
__global__ void __launch_bounds__(NT) k_init() {
  zfill(&g_h[0][0][0], 2L*NB*HH);
  zfill(&g_c[0][0], (long)NB*HH);
  zfill(&g_lr[0][0], (long)NB*INP);
  zfill(&g_usage[0][0], (long)NB*MM);
  zfill(&g_ww[0][0], (long)NB*MM);
  zfill(&g_prec[0][0][0], 2L*NB*MM);
  zfill(&g_rw[0][0][0], (long)NB*RH*MM);
  zfill(&g_mem[0][0][0], (long)NB*MM*CWID);
  zfill(&g_L[0][0][0], (long)NB*MM*MM);
}

// ---------------- Phase 1: gates GEMM (16x2048 @ K=1024) + fused LSTM --------
// WG w owns j-pair {2w,2w+1} across all 4 gates (8 rows). Two K-passes.
// Weights staged with nontemporal loads: stream-once data must not evict L/mem.
__global__ void __launch_bounds__(NT) k_ph1(P p, int t) {
  __shared__ __align__(16) float sm[14432];
  float* As  = sm;            // [16][AP]
  float* Ws  = sm + 16*AP;    // [8][AP]
  float* red = sm + 24*AP;    // [2048]
  const int tid = threadIdx.x;
  const int j0  = 2 * (int)blockIdx.x;
  const int op  = tid & 3;          // o-pair index (4)
  const int bq  = (tid >> 2) & 3;   // b-quad (4)
  const int ks  = tid >> 4;         // k-slice (16) of 32 per pass
  const float (*hsrc)[HH] = g_h[t & 1];
  float acc0[4] = {0.f,0.f,0.f,0.f};
  float acc1[4] = {0.f,0.f,0.f,0.f};
  for (int pass = 0; pass < 2; ++pass) {
    if (pass == 0) {
      for (int idx = tid; idx < NB*INP; idx += NT) {
        int b = idx >> 8, k = idx & 255;
        As[b*AP + k] = p.x[((size_t)b*TT + t)*INP + k];
      }
      for (int idx = tid; idx < NB*INP; idx += NT) {
        int b = idx >> 8, k = idx & 255;
        As[b*AP + INP + k] = g_lr[b][k];
      }
    } else {
      for (int idx = tid; idx < NB*HH; idx += NT) {
        int b = idx >> 9, k = idx & 511;
        As[b*AP + k] = hsrc[b][k];
      }
    }
    const float* Wsrc = pass ? p.W_hh : p.W_ih;
    for (int idx = tid; idx < 8*512; idx += NT) {
      int ro = idx >> 9, k = idx & 511;
      int row = (ro >> 1)*HH + j0 + (ro & 1);
      Ws[ro*AP + k] = NTLOAD(&Wsrc[(size_t)row*512 + k]);
    }
    __syncthreads();
    const int k0 = ks * 32;
    #pragma unroll
    for (int k4 = 0; k4 < 32; k4 += 4) {
      const float4 w0 = *(const float4*)&Ws[(op*2+0)*AP + k0 + k4];
      const float4 w1 = *(const float4*)&Ws[(op*2+1)*AP + k0 + k4];
      #pragma unroll
      for (int bb = 0; bb < 4; ++bb) {
        const float4 a = *(const float4*)&As[(bq*4+bb)*AP + k0 + k4];
        acc0[bb] += a.x*w0.x + a.y*w0.y + a.z*w0.z + a.w*w0.w;
        acc1[bb] += a.x*w1.x + a.y*w1.y + a.z*w1.z + a.w*w1.w;
      }
    }
    __syncthreads();  // protect LDS restage
  }
  #pragma unroll
  for (int bb = 0; bb < 4; ++bb) {
    red[(op*2+0)*256 + (bq*4+bb)*16 + ks] = acc0[bb];
    red[(op*2+1)*256 + (bq*4+bb)*16 + ks] = acc1[bb];
  }
  __syncthreads();
  if (tid < 128) {  // (8 rows x 16 b): reduce 16 k-slices + biases
    int o = tid >> 4, b = tid & 15;
    float s = 0.f;
    #pragma unroll
    for (int q = 0; q < 16; ++q) s += red[o*256 + b*16 + q];
    int row = (o >> 1)*HH + j0 + (o & 1);
    red[o*256 + b*16] = s + p.b_ih[row] + p.b_hh[row];
  }
  __syncthreads();
  if (tid < 32) {  // fused LSTM pointwise for (2 j) x (16 b)
    int jj = tid >> 4, b = tid & 15;
    int j  = j0 + jj;
    float gi = red[(0+jj)*256 + b*16];
    float gf = red[(2+jj)*256 + b*16];
    float gg = red[(4+jj)*256 + b*16];
    float go = red[(6+jj)*256 + b*16];
    float c0 = g_c[b][j];
    float cn = sigf(gf)*c0 + sigf(gi)*tanhf(gg);
    float hn = sigf(go)*tanhf(cn);
    g_c[b][j] = cn;
    g_h[(t+1) & 1][b][j] = hn;
  }
}

// ---------------- Phase 2: out = h@W_out^T, xi = h@W_int^T -------------------
__global__ void __launch_bounds__(NT) k_ph2(P p, int t) {
  __shared__ __align__(16) float sm[10576];
  float* hs  = sm;            // [16][AP]
  float* Ws  = sm + 16*AP;    // [4][AP]
  float* red = sm + 20*AP;    // 256
  const int tid = threadIdx.x;
  const int o0  = 4 * (int)blockIdx.x;   // 1024 virtual outputs (512 out + 471 xi + pad)
  const float (*hcur)[HH] = g_h[(t+1) & 1];
  for (int idx = tid; idx < NB*HH; idx += NT) {
    int b = idx >> 9, k = idx & 511;
    hs[b*AP + k] = hcur[b][k];
  }
  for (int idx = tid; idx < 4*512; idx += NT) {
    int oi = idx >> 9, k = idx & 511;
    int o = o0 + oi;
    float v = 0.f;
    if (o < HH)              v = NTLOAD(&p.W_out[(size_t)o*512 + k]);
    else if (o < HH + IFACE) v = NTLOAD(&p.W_int[(size_t)(o - HH)*512 + k]);
    Ws[oi*AP + k] = v;
  }
  __syncthreads();
  {
    const int b = tid & 15, oi = (tid >> 4) & 3, ks = tid >> 6;
    const int k0 = ks * 128;
    float acc = 0.f;
    #pragma unroll 8
    for (int k4 = 0; k4 < 128; k4 += 4) {
      const float4 a  = *(const float4*)&hs[b*AP + k0 + k4];
      const float4 wv = *(const float4*)&Ws[oi*AP + k0 + k4];
      acc += a.x*wv.x + a.y*wv.y + a.z*wv.z + a.w*wv.w;
    }
    red[(oi*16 + b)*4 + ks] = acc;
  }
  __syncthreads();
  if (tid < 64) {
    int oi = tid >> 4, b = tid & 15;
    int base = (oi*16 + b)*4;
    float s = red[base] + red[base+1] + red[base+2] + red[base+3];
    int o = o0 + oi;
    if (o < HH) g_out[b][o] = s + p.b_out[o];
    else if (o < HH + IFACE) g_xi[b][o - HH] = s + p.b_int[o - HH];
  }
}

// ------- Phase 3 (16 WGs x 512 thr, one WG per batch): parse xi, usage,
// ------- write-content softmax, allocation (rank sort + wave-scan cumprod),
// ------- write weights, precedence.
__global__ void __launch_bounds__(512) k_ph3(int pp) {
  __shared__ __align__(16) float sm[4152];
  const int b = (int)blockIdx.x, tid = threadIdx.x;
  float* xi_l = sm;            // 472
  float* wkn  = sm + 472;      // 64
  float* sc   = sm + 536;      // 16: [0..3]=rs [4..7]=free [8]=ag [9]=wg [10]=ws
  float* u_l  = sm + 552;      // 512
  float* wcw  = sm + 1064;     // 512
  float* su   = sm + 1576;     // 512
  float* cB   = sm + 2600;     // 512 (inclusive cumprod)
  float* wwl  = sm + 3112;     // 512
  float* red  = sm + 3624;     // 16
  int*   rnk  = (int*)(sm + 3640); // 512

  for (int i = tid; i < IFACE; i += 512) xi_l[i] = g_xi[b][i];
  __syncthreads();
  {
    const int wv = tid >> 6, v = tid & 63;
    if (wv < 4) {           // read keys r=wv: normalize
      float kv = tanhf(xi_l[wv*64 + v]);
      float ss = kv * kv;
      #pragma unroll
      for (int d = 1; d < 64; d <<= 1) ss += __shfl_xor(ss, d, 64);
      g_rkn[b][wv][v] = kv / (sqrtf(ss) + DELTA);
      if (v == 0) { float s_ = splus(xi_l[256 + wv]); sc[wv] = s_; g_rs[b][wv] = s_; }
    } else if (wv == 4) {   // write key: normalize
      float kv = tanhf(xi_l[260 + v]);
      float ss = kv * kv;
      #pragma unroll
      for (int d = 1; d < 64; d <<= 1) ss += __shfl_xor(ss, d, 64);
      wkn[v] = kv / (sqrtf(ss) + DELTA);
    } else if (wv == 5) {
      g_erase[b][v] = sigf(xi_l[325 + v]);
    } else if (wv == 6) {
      g_wv[b][v] = tanhf(xi_l[389 + v]);
    } else {
      if (v < 4)       sc[4 + v] = sigf(xi_l[453 + v]);   // free gates
      else if (v == 4) sc[8] = sigf(xi_l[457]);           // alloc gate
      else if (v == 5) sc[9] = sigf(xi_l[458]);           // write gate
      else if (v == 6) sc[10] = splus(xi_l[324]);         // write strength
      else if (v >= 8 && v < 12) {                        // read modes softmax
        int r = v - 8;
        float a0 = xi_l[459 + r*3], a1 = xi_l[459 + r*3 + 1], a2 = xi_l[459 + r*3 + 2];
        float mx = fmaxf(a0, fmaxf(a1, a2));
        float e0 = __expf(a0 - mx), e1 = __expf(a1 - mx), e2 = __expf(a2 - mx);
        float si = e0 + e1 + e2;
        g_modes[b][r][0] = e0/si; g_modes[b][r][1] = e1/si; g_modes[b][r][2] = e2/si;
      }
    }
  }
  __syncthreads();
  // usage update (uses PREV write_w & read_w); one slot per thread
  {
    float uo = g_usage[b][tid];
    float wwp = g_ww[b][tid];
    float psi = 1.f;
    #pragma unroll
    for (int r = 0; r < RH; ++r) psi *= 1.f - sc[4+r]*g_rw[b][r][tid];
    float un = (uo + (1.f - uo)*wwp) * psi;
    g_usage[b][tid] = un;
    u_l[tid] = DELTA + (1.f - DELTA)*un;
  }
  // write-content logits vs OLD memory; one row per thread
  {
    float dot = 0.f, nn = 0.f;
    const float* mr = &g_mem[b][tid][0];
    #pragma unroll
    for (int v4 = 0; v4 < CWID; v4 += 4) {
      float4 m4 = *(const float4*)&mr[v4];
      dot += m4.x*wkn[v4] + m4.y*wkn[v4+1] + m4.z*wkn[v4+2] + m4.w*wkn[v4+3];
      nn  += m4.x*m4.x + m4.y*m4.y + m4.z*m4.z + m4.w*m4.w;
    }
    wcw[tid] = (dot / (sqrtf(nn) + DELTA)) * sc[10];
  }
  __syncthreads();
  {  // softmax over 512 (8 waves)
    const int wv = tid >> 6, v = tid & 63;
    float x0 = wcw[tid];
    float mx = x0;
    #pragma unroll
    for (int d = 1; d < 64; d <<= 1) mx = fmaxf(mx, __shfl_xor(mx, d, 64));
    if (v == 0) red[wv] = mx;
    __syncthreads();
    float gmx = red[0];
    #pragma unroll
    for (int q = 1; q < 8; ++q) gmx = fmaxf(gmx, red[q]);
    float e0 = __expf(x0 - gmx);
    float ss = e0;
    #pragma unroll
    for (int d = 1; d < 64; d <<= 1) ss += __shfl_xor(ss, d, 64);
    if (v == 0) red[8 + wv] = ss;
    __syncthreads();
    float tot = red[8];
    #pragma unroll
    for (int q = 9; q < 16; ++q) tot += red[q];
    wcw[tid] = e0 / tot;
  }
  __syncthreads();
  {  // stable rank via vectorized count (float4 LDS broadcasts, high ILP)
    const float u0 = u_l[tid];
    int cnt = 0;
    for (int j = 0; j < MM; j += 8) {
      const float4 a = *(const float4*)&u_l[j];
      const float4 c = *(const float4*)&u_l[j + 4];
      cnt += (a.x < u0) || (a.x == u0 && (j+0) < tid);
      cnt += (a.y < u0) || (a.y == u0 && (j+1) < tid);
      cnt += (a.z < u0) || (a.z == u0 && (j+2) < tid);
      cnt += (a.w < u0) || (a.w == u0 && (j+3) < tid);
      cnt += (c.x < u0) || (c.x == u0 && (j+4) < tid);
      cnt += (c.y < u0) || (c.y == u0 && (j+5) < tid);
      cnt += (c.z < u0) || (c.z == u0 && (j+6) < tid);
      cnt += (c.w < u0) || (c.w == u0 && (j+7) < tid);
    }
    rnk[tid] = cnt;
    su[cnt] = u0;   // ranks are a permutation -> no collisions
  }
  __syncthreads();
  {  // inclusive cumprod of sorted u via wave-scan + wave-prefix (2 barriers)
    const int lane = tid & 63, wv = tid >> 6;
    float v = su[tid];
    #pragma unroll
    for (int d = 1; d < 64; d <<= 1) {
      float m = __shfl_up(v, d, 64);
      if (lane >= d) v *= m;
    }
    if (lane == 63) red[wv] = v;  // wave totals
    __syncthreads();
    float pre = 1.f;
    for (int q = 0; q < wv; ++q) pre *= red[q];
    cB[tid] = v * pre;            // inclusive cumprod
    __syncthreads();
    float ag = sc[8], wgt = sc[9];
    int rk = rnk[tid];
    float excl = rk ? cB[rk - 1] : 1.f;   // exclusive cumprod at this row's rank
    float alloc = (1.f - u_l[tid]) * excl;
    float wn = wgt * (ag*alloc + (1.f - ag)*wcw[tid]);
    wwl[tid] = wn;
    g_ww[b][tid] = wn;
  }
  __syncthreads();
  {  // precedence update into OTHER buffer (phase4 needs OLD prec)
    const int wv = tid >> 6, v = tid & 63;
    float s2 = wwl[tid];
    #pragma unroll
    for (int d = 1; d < 64; d <<= 1) s2 += __shfl_xor(s2, d, 64);
    if (v == 0) red[wv] = s2;
    __syncthreads();
    float sww = red[0];
    #pragma unroll
    for (int q = 1; q < 8; ++q) sww += red[q];
    g_prec[1 - pp][b][tid] = (1.f - sww)*g_prec[pp][b][tid] + wwl[tid];
  }
}

// ------- Phase 4: WG (b, 32-row slice): link update + fwd + bwd partials,
// ------- memory write, read-content exp (unnormalized) + partial sums.
// ------- js-rotated column order: LDS operand banks spread 8-way -> 2-way.
__global__ void __launch_bounds__(NT) k_ph4(int pp) {
  __shared__ __align__(16) float sm[6608];
  const int w = (int)blockIdx.x, tid = threadIdx.x;
  const int b = w >> 4, s = w & 15, i0 = s * 32;
  float* pl   = sm;            // 512  old precedence
  float* wwl  = sm + 512;      // 512  new write weights
  float* rwl  = sm + 1024;     // 2048 prev read weights [r][j]
  float* el   = sm + 3072;     // 64
  float* wvl  = sm + 3136;     // 64
  float* rknl = sm + 3200;     // 256
  float* rs4  = sm + 3456;     // 16
  float* fp   = sm + 3472;     // 1024 scratch partials
  float* mt   = sm + 4496;     // 2080 new memory rows [32][65]
  float* nrm  = sm + 6576;     // 32

  for (int i = tid; i < MM; i += NT) { pl[i] = g_prec[pp][b][i]; wwl[i] = g_ww[b][i]; }
  for (int i = tid; i < RH*MM; i += NT) rwl[i] = g_rw[b][i >> 9][i & 511];
  for (int i = tid; i < CWID; i += NT) { el[i] = g_erase[b][i]; wvl[i] = g_wv[b][i]; }
  for (int i = tid; i < RH*CWID; i += NT) rknl[i] = g_rkn[b][i >> 6][i & 63];
  if (tid < 4) rs4[tid] = g_rs[b][tid];
  __syncthreads();
  {  // L update (in place, own rows) + fwd partials; js-rotation kills
     // the 8-way same-bank reads (js*64 % 32 == 0 for all js).
    const int ii = tid >> 3, js = tid & 7;
    const int i = i0 + ii;
    const float wwi = wwl[i];
    float f0=0.f, f1=0.f, f2=0.f, f3=0.f;
    float* Lrow = &g_L[b][i][0];
    #pragma unroll
    for (int step = 0; step < 16; ++step) {
      const int col = js*64 + ((js*8 + step*4) & 63);
      float4 l4 = *(float4*)&Lrow[col];
      float lv[4] = {l4.x, l4.y, l4.z, l4.w};
      #pragma unroll
      for (int q = 0; q < 4; ++q) {
        const int jq = col + q;
        float lnv = (1.f - wwi - wwl[jq]) * lv[q] + wwi * pl[jq];
        if (jq == i) lnv = 0.f;
        lv[q] = lnv;
        f0 += lnv * rwl[jq];
        f1 += lnv * rwl[512 + jq];
        f2 += lnv * rwl[1024 + jq];
        f3 += lnv * rwl[1536 + jq];
      }
      *(float4*)&Lrow[col] = make_float4(lv[0], lv[1], lv[2], lv[3]);
    }
    fp[(ii*8 + js)*4 + 0] = f0;
    fp[(ii*8 + js)*4 + 1] = f1;
    fp[(ii*8 + js)*4 + 2] = f2;
    fp[(ii*8 + js)*4 + 3] = f3;
  }
  __syncthreads();
  if (tid < 128) {  // fwd reduce
    int ii = tid >> 2, r = tid & 3;
    float sY = 0.f;
    #pragma unroll
    for (int js = 0; js < 8; ++js) sY += fp[(ii*8 + js)*4 + r];
    g_fwd[b][r][i0 + ii] = sY;
  }
  {  // bwd partials over own rows (rows just written by THIS WG, post-sync)
    const int j = tid * 2;
    float a00=0,a01=0,a10=0,a11=0,a20=0,a21=0,a30=0,a31=0;
    #pragma unroll 4
    for (int ii2 = 0; ii2 < 32; ++ii2) {
      const int i = i0 + ii2;
      const float2 l2 = *(const float2*)&g_L[b][i][j];
      const float r0 = rwl[i], r1 = rwl[512+i], r2 = rwl[1024+i], r3 = rwl[1536+i];
      a00 += r0*l2.x; a01 += r0*l2.y;
      a10 += r1*l2.x; a11 += r1*l2.y;
      a20 += r2*l2.x; a21 += r2*l2.y;
      a30 += r3*l2.x; a31 += r3*l2.y;
    }
    g_bwdp[b][s][0][j] = a00; g_bwdp[b][s][0][j+1] = a01;
    g_bwdp[b][s][1][j] = a10; g_bwdp[b][s][1][j+1] = a11;
    g_bwdp[b][s][2][j] = a20; g_bwdp[b][s][2][j+1] = a21;
    g_bwdp[b][s][3][j] = a30; g_bwdp[b][s][3][j+1] = a31;
  }
  // memory write (own rows)
  for (int idx = tid; idx < 32*CWID; idx += NT) {
    int ii = idx >> 6, v = idx & 63;
    int i = i0 + ii;
    float wwi = wwl[i];
    float mv = g_mem[b][i][v];
    float mn = mv * (1.f - wwi*el[v]) + wwi*wvl[v];
    g_mem[b][i][v] = mn;
    mt[ii*65 + v] = mn;
  }
  __syncthreads();
  {  // row norms of new memory
    int ii = tid >> 3, js = tid & 7;
    float nn = 0.f;
    #pragma unroll
    for (int q = 0; q < 8; ++q) { float mv = mt[ii*65 + js*8 + q]; nn += mv*mv; }
    fp[(ii*8 + js)*4] = nn;
  }
  __syncthreads();
  if (tid < 32) {
    float nn = 0.f;
    #pragma unroll
    for (int q = 0; q < 8; ++q) nn += fp[(tid*8 + q)*4];
    nrm[tid] = sqrtf(nn) + DELTA;
  }
  __syncthreads();
  {  // read-content dot partials vs new memory
    int ii = tid >> 3, js = tid & 7;
    float p0=0,p1=0,p2=0,p3=0;
    #pragma unroll
    for (int q = 0; q < 8; ++q) {
      float mv = mt[ii*65 + js*8 + q];
      p0 += mv * rknl[ 0 + js*8 + q];
      p1 += mv * rknl[ 64 + js*8 + q];
      p2 += mv * rknl[128 + js*8 + q];
      p3 += mv * rknl[192 + js*8 + q];
    }
    fp[(ii*8 + js)*4 + 0] = p0;
    fp[(ii*8 + js)*4 + 1] = p1;
    fp[(ii*8 + js)*4 + 2] = p2;
    fp[(ii*8 + js)*4 + 3] = p3;
  }
  __syncthreads();
  if (tid < 128) {  // exp (logit = cos*strength, bounded -> no max-subtract)
    int ii = tid >> 2, r = tid & 3;
    float d = 0.f;
    #pragma unroll
    for (int js = 0; js < 8; ++js) d += fp[(ii*8 + js)*4 + r];
    float e = __expf((d / nrm[ii]) * rs4[r]);
    g_e[b][r][i0 + ii] = e;
    mt[ii*4 + r] = e;
  }
  __syncthreads();
  if (tid < 4) {
    float ssum = 0.f;
    #pragma unroll
    for (int q = 0; q < 32; ++q) ssum += mt[q*4 + tid];
    g_cwsp[b][s][tid] = ssum;
  }
}

// ------- Phase 5+6 fused: WG (b, o-slice s). Each WG redundantly computes
// ------- read weights (bwd reduce + modes mix) and read vectors from
// ------- L2-local data; s==0 WGs persist g_rw / g_lr; all WGs emit their
// ------- 16-output y slice.
__global__ void __launch_bounds__(NT) k_ph56(P p, int t) {
  __shared__ __align__(16) float sm[3072];
  const int w = (int)blockIdx.x, tid = threadIdx.x;
  const int b = w >> 4, s = w & 15, o0 = s * 16;
  float* rwl  = sm;          // [4][512]
  float* rvl  = sm + 2048;   // 256
  float* outl = sm + 2304;   // 512
  float* red  = sm + 2816;   // 256
  // denominators of read-content softmax (wave-uniform loads -> broadcast)
  float Sr[4];
  #pragma unroll
  for (int r = 0; r < 4; ++r) {
    float ss = 0.f;
    #pragma unroll
    for (int q = 0; q < 16; ++q) ss += g_cwsp[b][q][r];
    Sr[r] = ss;
  }
  // read weights: thread handles j = tid, tid+256
  for (int jj = tid; jj < MM; jj += NT) {
    #pragma unroll
    for (int r = 0; r < 4; ++r) {
      float bw = 0.f;
      #pragma unroll
      for (int q = 0; q < 16; ++q) bw += g_bwdp[b][q][r][jj];
      float fw = g_fwd[b][r][jj];
      float cwv = g_e[b][r][jj] / Sr[r];
      float rn = g_modes[b][r][0]*bw + g_modes[b][r][1]*fw + g_modes[b][r][2]*cwv;
      rwl[r*512 + jj] = rn;
      if (s == 0) g_rw[b][r][jj] = rn;
    }
  }
  for (int k = tid; k < HH; k += NT) outl[k] = g_out[b][k];
  __syncthreads();
  {  // read vectors: thread (r,v), full K=512 (rwl broadcast, mem coalesced)
    int r = tid >> 6, v = tid & 63;
    float acc = 0.f;
    for (int j = 0; j < MM; ++j) acc += rwl[r*512 + j] * g_mem[b][j][v];
    rvl[r*64 + v] = acc;
    if (s == 0) g_lr[b][r*64 + v] = acc;   // last_read for next step
  }
  __syncthreads();
  {  // y slice: o = o0 + oi over K=768 (out || read_vecs)
    int oi = tid & 15, ks = tid >> 4;
    int o = o0 + oi;
    const float* wm = &p.W_mem[(size_t)o * 768];
    float acc = 0.f;
    for (int k = ks*48; k < ks*48 + 48; ++k) {
      float a = (k < HH) ? outl[k] : rvl[k - HH];
      acc += a * NTLOAD(&wm[k]);
    }
    red[oi*16 + ks] = acc;
  }
  __syncthreads();
  if (tid < 16) {
    int o = o0 + tid;
    float ss = 0.f;
    #pragma unroll
    for (int q = 0; q < 16; ++q) ss += red[tid*16 + q];
    p.y[((size_t)b*TT + t)*INP + o] = ss + p.b_mem[o];
  }
}

extern "C" void kernel_launch(void* const* d_in, const int* in_sizes, int n_in,
                              void* d_out, int out_size, void* d_ws, size_t ws_size,
                              hipStream_t stream) {
  (void)in_sizes; (void)n_in; (void)out_size; (void)d_ws; (void)ws_size;
  P p;
  p.x     = (const float*)d_in[0];
  p.W_ih  = (const float*)d_in[1];
  p.b_ih  = (const float*)d_in[2];
  p.W_hh  = (const float*)d_in[3];
  p.b_hh  = (const float*)d_in[4];
  p.W_out = (const float*)d_in[5];
  p.b_out = (const float*)d_in[6];
  p.W_int = (const float*)d_in[7];
  p.b_int = (const float*)d_in[8];
  p.W_mem = (const float*)d_in[9];
  p.b_mem = (const float*)d_in[10];
  p.y     = (float*)d_out;

  k_init<<<dim3(1024), dim3(NT), 0, stream>>>();
  for (int t = 0; t < TT; ++t) {
    const int pp = t & 1;
    k_ph1<<<dim3(NWG), dim3(NT), 0, stream>>>(p, t);
    k_ph2<<<dim3(NWG), dim3(NT), 0, stream>>>(p, t);
    k_ph3<<<dim3(NB),  dim3(512), 0, stream>>>(pp);
    k_ph4<<<dim3(NWG), dim3(NT), 0, stream>>>(pp);
    k_ph56<<<dim3(NWG), dim3(NT), 0, stream>>>(p, t);
  }
}

// Round 6
// 2142.451 us; speedup vs baseline: 1.4075x; 1.4075x over previous
//
#include <hip/hip_runtime.h>
#include <math.h>

#define NB 16        // batch
#define NT 256       // threads per workgroup
#define NWG 256      // workgroups for wide phases
#define TT 32        // timesteps
#define INP 256
#define HH 512
#define RH 4
#define CWID 64
#define MM 512
#define IFACE 471
#define DELTA 1e-6f
#define AP 516       // padded LDS row stride (fp32) for 512-wide tiles

// ---------------- persistent device state (avoids ws_size assumptions) -------
__device__ __align__(16) float g_h[2][NB][HH];   // double-buffered across phase1
__device__ __align__(16) float g_c[NB][HH];
__device__ __align__(16) float g_lr[NB][INP];
__device__ __align__(16) float g_usage[NB][MM];
__device__ __align__(16) float g_ww[NB][MM];
__device__ __align__(16) float g_prec[2][NB][MM]; // double-buffered: L-update needs OLD prec
__device__ __align__(16) float g_rw[NB][RH][MM];
__device__ __align__(16) float g_mem[NB][MM][CWID];
__device__ __align__(16) float g_L[NB][MM][MM];   // 16.8 MB, partitioned (b, 32-row slice)
__device__ __align__(16) float g_out[NB][HH];
__device__ __align__(16) float g_xi[NB][HH];
__device__ __align__(16) float g_rkn[NB][RH][CWID]; // normalized read keys
__device__ __align__(16) float g_rs[NB][RH];
__device__ __align__(16) float g_erase[NB][CWID];
__device__ __align__(16) float g_wv[NB][CWID];
__device__ __align__(16) float g_modes[NB][RH][3];
__device__ __align__(16) float g_fwd[NB][RH][MM];
__device__ __align__(16) float g_bwdp[NB][16][RH][MM]; // bwd partials per row-slice
__device__ __align__(16) float g_e[NB][RH][MM];        // unnormalized read-content exp
__device__ __align__(16) float g_cwsp[NB][16][RH];     // partial sums of g_e
__device__ __align__(16) float g_rvp[NB][16][RH][CWID];// read-vector partials

struct P {
  const float *x, *W_ih, *b_ih, *W_hh, *b_hh, *W_out, *b_out, *W_int, *b_int, *W_mem, *b_mem;
  float* y;
};

__device__ __forceinline__ float sigf(float x)  { return 1.f / (1.f + __expf(-x)); }
__device__ __forceinline__ float splus(float x) { return fmaxf(x, 0.f) + log1pf(__expf(-fabsf(x))); }

__device__ __forceinline__ void zfill(float* a, long n) {
  const long stride = (long)gridDim.x * blockDim.x;
  for (long i = (long)blockIdx.x * blockDim.x + threadIdx.x; i < n; i += stride) a[i] = 0.f;
}

// ---------------- init: deterministic re-zero of all carried state ----------
__global__ void __launch_bounds__(NT) k_init() {
  zfill(&g_h[0][0][0], 2L*NB*HH);
  zfill(&g_c[0][0], (long)NB*HH);
  zfill(&g_lr[0][0], (long)NB*INP);
  zfill(&g_usage[0][0], (long)NB*MM);
  zfill(&g_ww[0][0], (long)NB*MM);
  zfill(&g_prec[0][0][0], 2L*NB*MM);
  zfill(&g_rw[0][0][0], (long)NB*RH*MM);
  zfill(&g_mem[0][0][0], (long)NB*MM*CWID);
  zfill(&g_L[0][0][0], (long)NB*MM*MM);
}

// ---------------- Phase 1: gates GEMM (16x2048 @ K=1024) + fused LSTM --------
// WG w owns j-pair {2w,2w+1} across all 4 gates (8 rows). Two K-passes.
// Plain loads for weights: each WG re-reads the SAME slice every step ->
// L2-resident by design (NT hint defeats this; R5 lesson).
__global__ void __launch_bounds__(NT) k_ph1(P p, int t) {
  __shared__ __align__(16) float sm[14432];
  float* As  = sm;            // [16][AP]
  float* Ws  = sm + 16*AP;    // [8][AP]
  float* red = sm + 24*AP;    // [2048]
  const int tid = threadIdx.x;
  const int j0  = 2 * (int)blockIdx.x;
  const int op  = tid & 3;          // o-pair index (4)
  const int bq  = (tid >> 2) & 3;   // b-quad (4)
  const int ks  = tid >> 4;         // k-slice (16) of 32 per pass
  const float (*hsrc)[HH] = g_h[t & 1];
  float acc0[4] = {0.f,0.f,0.f,0.f};
  float acc1[4] = {0.f,0.f,0.f,0.f};
  for (int pass = 0; pass < 2; ++pass) {
    if (pass == 0) {
      for (int idx = tid; idx < NB*INP; idx += NT) {
        int b = idx >> 8, k = idx & 255;
        As[b*AP + k] = p.x[((size_t)b*TT + t)*INP + k];
      }
      for (int idx = tid; idx < NB*INP; idx += NT) {
        int b = idx >> 8, k = idx & 255;
        As[b*AP + INP + k] = g_lr[b][k];
      }
    } else {
      for (int idx = tid; idx < NB*HH; idx += NT) {
        int b = idx >> 9, k = idx & 511;
        As[b*AP + k] = hsrc[b][k];
      }
    }
    const float* Wsrc = pass ? p.W_hh : p.W_ih;
    for (int idx = tid; idx < 8*512; idx += NT) {
      int ro = idx >> 9, k = idx & 511;
      int row = (ro >> 1)*HH + j0 + (ro & 1);
      Ws[ro*AP + k] = Wsrc[(size_t)row*512 + k];
    }
    __syncthreads();
    const int k0 = ks * 32;
    #pragma unroll
    for (int k4 = 0; k4 < 32; k4 += 4) {
      const float4 w0 = *(const float4*)&Ws[(op*2+0)*AP + k0 + k4];
      const float4 w1 = *(const float4*)&Ws[(op*2+1)*AP + k0 + k4];
      #pragma unroll
      for (int bb = 0; bb < 4; ++bb) {
        const float4 a = *(const float4*)&As[(bq*4+bb)*AP + k0 + k4];
        acc0[bb] += a.x*w0.x + a.y*w0.y + a.z*w0.z + a.w*w0.w;
        acc1[bb] += a.x*w1.x + a.y*w1.y + a.z*w1.z + a.w*w1.w;
      }
    }
    __syncthreads();  // protect LDS restage
  }
  #pragma unroll
  for (int bb = 0; bb < 4; ++bb) {
    red[(op*2+0)*256 + (bq*4+bb)*16 + ks] = acc0[bb];
    red[(op*2+1)*256 + (bq*4+bb)*16 + ks] = acc1[bb];
  }
  __syncthreads();
  if (tid < 128) {  // (8 rows x 16 b): reduce 16 k-slices + biases
    int o = tid >> 4, b = tid & 15;
    float s = 0.f;
    #pragma unroll
    for (int q = 0; q < 16; ++q) s += red[o*256 + b*16 + q];
    int row = (o >> 1)*HH + j0 + (o & 1);
    red[o*256 + b*16] = s + p.b_ih[row] + p.b_hh[row];
  }
  __syncthreads();
  if (tid < 32) {  // fused LSTM pointwise for (2 j) x (16 b)
    int jj = tid >> 4, b = tid & 15;
    int j  = j0 + jj;
    float gi = red[(0+jj)*256 + b*16];
    float gf = red[(2+jj)*256 + b*16];
    float gg = red[(4+jj)*256 + b*16];
    float go = red[(6+jj)*256 + b*16];
    float c0 = g_c[b][j];
    float cn = sigf(gf)*c0 + sigf(gi)*tanhf(gg);
    float hn = sigf(go)*tanhf(cn);
    g_c[b][j] = cn;
    g_h[(t+1) & 1][b][j] = hn;
  }
}

// ---------------- Phase 2: out = h@W_out^T, xi = h@W_int^T -------------------
__global__ void __launch_bounds__(NT) k_ph2(P p, int t) {
  __shared__ __align__(16) float sm[10576];
  float* hs  = sm;            // [16][AP]
  float* Ws  = sm + 16*AP;    // [4][AP]
  float* red = sm + 20*AP;    // 256
  const int tid = threadIdx.x;
  const int o0  = 4 * (int)blockIdx.x;   // 1024 virtual outputs (512 out + 471 xi + pad)
  const float (*hcur)[HH] = g_h[(t+1) & 1];
  for (int idx = tid; idx < NB*HH; idx += NT) {
    int b = idx >> 9, k = idx & 511;
    hs[b*AP + k] = hcur[b][k];
  }
  for (int idx = tid; idx < 4*512; idx += NT) {
    int oi = idx >> 9, k = idx & 511;
    int o = o0 + oi;
    float v = 0.f;
    if (o < HH)              v = p.W_out[(size_t)o*512 + k];
    else if (o < HH + IFACE) v = p.W_int[(size_t)(o - HH)*512 + k];
    Ws[oi*AP + k] = v;
  }
  __syncthreads();
  {
    const int b = tid & 15, oi = (tid >> 4) & 3, ks = tid >> 6;
    const int k0 = ks * 128;
    float acc = 0.f;
    #pragma unroll 8
    for (int k4 = 0; k4 < 128; k4 += 4) {
      const float4 a  = *(const float4*)&hs[b*AP + k0 + k4];
      const float4 wv = *(const float4*)&Ws[oi*AP + k0 + k4];
      acc += a.x*wv.x + a.y*wv.y + a.z*wv.z + a.w*wv.w;
    }
    red[(oi*16 + b)*4 + ks] = acc;
  }
  __syncthreads();
  if (tid < 64) {
    int oi = tid >> 4, b = tid & 15;
    int base = (oi*16 + b)*4;
    float s = red[base] + red[base+1] + red[base+2] + red[base+3];
    int o = o0 + oi;
    if (o < HH) g_out[b][o] = s + p.b_out[o];
    else if (o < HH + IFACE) g_xi[b][o - HH] = s + p.b_int[o - HH];
  }
}

// ------- Phase 3 (16 WGs x 512 thr, one WG per batch): parse xi, usage,
// ------- write-content softmax, allocation (rank sort + wave-scan cumprod),
// ------- write weights, precedence.
__global__ void __launch_bounds__(512) k_ph3(int pp) {
  __shared__ __align__(16) float sm[4152];
  const int b = (int)blockIdx.x, tid = threadIdx.x;
  float* xi_l = sm;            // 472
  float* wkn  = sm + 472;      // 64
  float* sc   = sm + 536;      // 16: [0..3]=rs [4..7]=free [8]=ag [9]=wg [10]=ws
  float* u_l  = sm + 552;      // 512
  float* wcw  = sm + 1064;     // 512
  float* su   = sm + 1576;     // 512
  float* cB   = sm + 2600;     // 512 (inclusive cumprod)
  float* wwl  = sm + 3112;     // 512
  float* red  = sm + 3624;     // 16
  int*   rnk  = (int*)(sm + 3640); // 512

  for (int i = tid; i < IFACE; i += 512) xi_l[i] = g_xi[b][i];
  __syncthreads();
  {
    const int wv = tid >> 6, v = tid & 63;
    if (wv < 4) {           // read keys r=wv: normalize
      float kv = tanhf(xi_l[wv*64 + v]);
      float ss = kv * kv;
      #pragma unroll
      for (int d = 1; d < 64; d <<= 1) ss += __shfl_xor(ss, d, 64);
      g_rkn[b][wv][v] = kv / (sqrtf(ss) + DELTA);
      if (v == 0) { float s_ = splus(xi_l[256 + wv]); sc[wv] = s_; g_rs[b][wv] = s_; }
    } else if (wv == 4) {   // write key: normalize
      float kv = tanhf(xi_l[260 + v]);
      float ss = kv * kv;
      #pragma unroll
      for (int d = 1; d < 64; d <<= 1) ss += __shfl_xor(ss, d, 64);
      wkn[v] = kv / (sqrtf(ss) + DELTA);
    } else if (wv == 5) {
      g_erase[b][v] = sigf(xi_l[325 + v]);
    } else if (wv == 6) {
      g_wv[b][v] = tanhf(xi_l[389 + v]);
    } else {
      if (v < 4)       sc[4 + v] = sigf(xi_l[453 + v]);   // free gates
      else if (v == 4) sc[8] = sigf(xi_l[457]);           // alloc gate
      else if (v == 5) sc[9] = sigf(xi_l[458]);           // write gate
      else if (v == 6) sc[10] = splus(xi_l[324]);         // write strength
      else if (v >= 8 && v < 12) {                        // read modes softmax
        int r = v - 8;
        float a0 = xi_l[459 + r*3], a1 = xi_l[459 + r*3 + 1], a2 = xi_l[459 + r*3 + 2];
        float mx = fmaxf(a0, fmaxf(a1, a2));
        float e0 = __expf(a0 - mx), e1 = __expf(a1 - mx), e2 = __expf(a2 - mx);
        float si = e0 + e1 + e2;
        g_modes[b][r][0] = e0/si; g_modes[b][r][1] = e1/si; g_modes[b][r][2] = e2/si;
      }
    }
  }
  __syncthreads();
  // usage update (uses PREV write_w & read_w); one slot per thread
  {
    float uo = g_usage[b][tid];
    float wwp = g_ww[b][tid];
    float psi = 1.f;
    #pragma unroll
    for (int r = 0; r < RH; ++r) psi *= 1.f - sc[4+r]*g_rw[b][r][tid];
    float un = (uo + (1.f - uo)*wwp) * psi;
    g_usage[b][tid] = un;
    u_l[tid] = DELTA + (1.f - DELTA)*un;
  }
  // write-content logits vs OLD memory; one row per thread
  {
    float dot = 0.f, nn = 0.f;
    const float* mr = &g_mem[b][tid][0];
    #pragma unroll
    for (int v4 = 0; v4 < CWID; v4 += 4) {
      float4 m4 = *(const float4*)&mr[v4];
      dot += m4.x*wkn[v4] + m4.y*wkn[v4+1] + m4.z*wkn[v4+2] + m4.w*wkn[v4+3];
      nn  += m4.x*m4.x + m4.y*m4.y + m4.z*m4.z + m4.w*m4.w;
    }
    wcw[tid] = (dot / (sqrtf(nn) + DELTA)) * sc[10];
  }
  __syncthreads();
  {  // softmax over 512 (8 waves)
    const int wv = tid >> 6, v = tid & 63;
    float x0 = wcw[tid];
    float mx = x0;
    #pragma unroll
    for (int d = 1; d < 64; d <<= 1) mx = fmaxf(mx, __shfl_xor(mx, d, 64));
    if (v == 0) red[wv] = mx;
    __syncthreads();
    float gmx = red[0];
    #pragma unroll
    for (int q = 1; q < 8; ++q) gmx = fmaxf(gmx, red[q]);
    float e0 = __expf(x0 - gmx);
    float ss = e0;
    #pragma unroll
    for (int d = 1; d < 64; d <<= 1) ss += __shfl_xor(ss, d, 64);
    if (v == 0) red[8 + wv] = ss;
    __syncthreads();
    float tot = red[8];
    #pragma unroll
    for (int q = 9; q < 16; ++q) tot += red[q];
    wcw[tid] = e0 / tot;
  }
  __syncthreads();
  {  // stable rank via vectorized count (float4 LDS broadcasts, high ILP)
    const float u0 = u_l[tid];
    int cnt = 0;
    for (int j = 0; j < MM; j += 8) {
      const float4 a = *(const float4*)&u_l[j];
      const float4 c = *(const float4*)&u_l[j + 4];
      cnt += (a.x < u0) || (a.x == u0 && (j+0) < tid);
      cnt += (a.y < u0) || (a.y == u0 && (j+1) < tid);
      cnt += (a.z < u0) || (a.z == u0 && (j+2) < tid);
      cnt += (a.w < u0) || (a.w == u0 && (j+3) < tid);
      cnt += (c.x < u0) || (c.x == u0 && (j+4) < tid);
      cnt += (c.y < u0) || (c.y == u0 && (j+5) < tid);
      cnt += (c.z < u0) || (c.z == u0 && (j+6) < tid);
      cnt += (c.w < u0) || (c.w == u0 && (j+7) < tid);
    }
    rnk[tid] = cnt;
    su[cnt] = u0;   // ranks are a permutation -> no collisions
  }
  __syncthreads();
  {  // inclusive cumprod of sorted u via wave-scan + wave-prefix (2 barriers)
    const int lane = tid & 63, wv = tid >> 6;
    float v = su[tid];
    #pragma unroll
    for (int d = 1; d < 64; d <<= 1) {
      float m = __shfl_up(v, d, 64);
      if (lane >= d) v *= m;
    }
    if (lane == 63) red[wv] = v;  // wave totals
    __syncthreads();
    float pre = 1.f;
    for (int q = 0; q < wv; ++q) pre *= red[q];
    cB[tid] = v * pre;            // inclusive cumprod
    __syncthreads();
    float ag = sc[8], wgt = sc[9];
    int rk = rnk[tid];
    float excl = rk ? cB[rk - 1] : 1.f;   // exclusive cumprod at this row's rank
    float alloc = (1.f - u_l[tid]) * excl;
    float wn = wgt * (ag*alloc + (1.f - ag)*wcw[tid]);
    wwl[tid] = wn;
    g_ww[b][tid] = wn;
  }
  __syncthreads();
  {  // precedence update into OTHER buffer (phase4 needs OLD prec)
    const int wv = tid >> 6, v = tid & 63;
    float s2 = wwl[tid];
    #pragma unroll
    for (int d = 1; d < 64; d <<= 1) s2 += __shfl_xor(s2, d, 64);
    if (v == 0) red[wv] = s2;
    __syncthreads();
    float sww = red[0];
    #pragma unroll
    for (int q = 1; q < 8; ++q) sww += red[q];
    g_prec[1 - pp][b][tid] = (1.f - sww)*g_prec[pp][b][tid] + wwl[tid];
  }
}

// ------- Phase 4: WG (b, 32-row slice): link update + fwd + bwd partials,
// ------- memory write, read-content exp (unnormalized) + partial sums.
// ------- js-rotated column order: LDS operand banks spread 8-way -> 2-way.
__global__ void __launch_bounds__(NT) k_ph4(int pp) {
  __shared__ __align__(16) float sm[6608];
  const int w = (int)blockIdx.x, tid = threadIdx.x;
  const int b = w >> 4, s = w & 15, i0 = s * 32;
  float* pl   = sm;            // 512  old precedence
  float* wwl  = sm + 512;      // 512  new write weights
  float* rwl  = sm + 1024;     // 2048 prev read weights [r][j]
  float* el   = sm + 3072;     // 64
  float* wvl  = sm + 3136;     // 64
  float* rknl = sm + 3200;     // 256
  float* rs4  = sm + 3456;     // 16
  float* fp   = sm + 3472;     // 1024 scratch partials
  float* mt   = sm + 4496;     // 2080 new memory rows [32][65]
  float* nrm  = sm + 6576;     // 32

  for (int i = tid; i < MM; i += NT) { pl[i] = g_prec[pp][b][i]; wwl[i] = g_ww[b][i]; }
  for (int i = tid; i < RH*MM; i += NT) rwl[i] = g_rw[b][i >> 9][i & 511];
  for (int i = tid; i < CWID; i += NT) { el[i] = g_erase[b][i]; wvl[i] = g_wv[b][i]; }
  for (int i = tid; i < RH*CWID; i += NT) rknl[i] = g_rkn[b][i >> 6][i & 63];
  if (tid < 4) rs4[tid] = g_rs[b][tid];
  __syncthreads();
  {  // L update (in place, own rows) + fwd partials; js-rotation kills
     // the 8-way same-bank reads (js*64 % 32 == 0 for all js).
    const int ii = tid >> 3, js = tid & 7;
    const int i = i0 + ii;
    const float wwi = wwl[i];
    float f0=0.f, f1=0.f, f2=0.f, f3=0.f;
    float* Lrow = &g_L[b][i][0];
    #pragma unroll
    for (int step = 0; step < 16; ++step) {
      const int col = js*64 + ((js*8 + step*4) & 63);
      float4 l4 = *(float4*)&Lrow[col];
      float lv[4] = {l4.x, l4.y, l4.z, l4.w};
      #pragma unroll
      for (int q = 0; q < 4; ++q) {
        const int jq = col + q;
        float lnv = (1.f - wwi - wwl[jq]) * lv[q] + wwi * pl[jq];
        if (jq == i) lnv = 0.f;
        lv[q] = lnv;
        f0 += lnv * rwl[jq];
        f1 += lnv * rwl[512 + jq];
        f2 += lnv * rwl[1024 + jq];
        f3 += lnv * rwl[1536 + jq];
      }
      *(float4*)&Lrow[col] = make_float4(lv[0], lv[1], lv[2], lv[3]);
    }
    fp[(ii*8 + js)*4 + 0] = f0;
    fp[(ii*8 + js)*4 + 1] = f1;
    fp[(ii*8 + js)*4 + 2] = f2;
    fp[(ii*8 + js)*4 + 3] = f3;
  }
  __syncthreads();
  if (tid < 128) {  // fwd reduce
    int ii = tid >> 2, r = tid & 3;
    float sY = 0.f;
    #pragma unroll
    for (int js = 0; js < 8; ++js) sY += fp[(ii*8 + js)*4 + r];
    g_fwd[b][r][i0 + ii] = sY;
  }
  {  // bwd partials over own rows (rows just written by THIS WG, post-sync)
    const int j = tid * 2;
    float a00=0,a01=0,a10=0,a11=0,a20=0,a21=0,a30=0,a31=0;
    #pragma unroll 4
    for (int ii2 = 0; ii2 < 32; ++ii2) {
      const int i = i0 + ii2;
      const float2 l2 = *(const float2*)&g_L[b][i][j];
      const float r0 = rwl[i], r1 = rwl[512+i], r2 = rwl[1024+i], r3 = rwl[1536+i];
      a00 += r0*l2.x; a01 += r0*l2.y;
      a10 += r1*l2.x; a11 += r1*l2.y;
      a20 += r2*l2.x; a21 += r2*l2.y;
      a30 += r3*l2.x; a31 += r3*l2.y;
    }
    g_bwdp[b][s][0][j] = a00; g_bwdp[b][s][0][j+1] = a01;
    g_bwdp[b][s][1][j] = a10; g_bwdp[b][s][1][j+1] = a11;
    g_bwdp[b][s][2][j] = a20; g_bwdp[b][s][2][j+1] = a21;
    g_bwdp[b][s][3][j] = a30; g_bwdp[b][s][3][j+1] = a31;
  }
  // memory write (own rows)
  for (int idx = tid; idx < 32*CWID; idx += NT) {
    int ii = idx >> 6, v = idx & 63;
    int i = i0 + ii;
    float wwi = wwl[i];
    float mv = g_mem[b][i][v];
    float mn = mv * (1.f - wwi*el[v]) + wwi*wvl[v];
    g_mem[b][i][v] = mn;
    mt[ii*65 + v] = mn;
  }
  __syncthreads();
  {  // row norms of new memory
    int ii = tid >> 3, js = tid & 7;
    float nn = 0.f;
    #pragma unroll
    for (int q = 0; q < 8; ++q) { float mv = mt[ii*65 + js*8 + q]; nn += mv*mv; }
    fp[(ii*8 + js)*4] = nn;
  }
  __syncthreads();
  if (tid < 32) {
    float nn = 0.f;
    #pragma unroll
    for (int q = 0; q < 8; ++q) nn += fp[(tid*8 + q)*4];
    nrm[tid] = sqrtf(nn) + DELTA;
  }
  __syncthreads();
  {  // read-content dot partials vs new memory
    int ii = tid >> 3, js = tid & 7;
    float p0=0,p1=0,p2=0,p3=0;
    #pragma unroll
    for (int q = 0; q < 8; ++q) {
      float mv = mt[ii*65 + js*8 + q];
      p0 += mv * rknl[ 0 + js*8 + q];
      p1 += mv * rknl[ 64 + js*8 + q];
      p2 += mv * rknl[128 + js*8 + q];
      p3 += mv * rknl[192 + js*8 + q];
    }
    fp[(ii*8 + js)*4 + 0] = p0;
    fp[(ii*8 + js)*4 + 1] = p1;
    fp[(ii*8 + js)*4 + 2] = p2;
    fp[(ii*8 + js)*4 + 3] = p3;
  }
  __syncthreads();
  if (tid < 128) {  // exp (logit = cos*strength, bounded -> no max-subtract)
    int ii = tid >> 2, r = tid & 3;
    float d = 0.f;
    #pragma unroll
    for (int js = 0; js < 8; ++js) d += fp[(ii*8 + js)*4 + r];
    float e = __expf((d / nrm[ii]) * rs4[r]);
    g_e[b][r][i0 + ii] = e;
    mt[ii*4 + r] = e;
  }
  __syncthreads();
  if (tid < 4) {
    float ssum = 0.f;
    #pragma unroll
    for (int q = 0; q < 32; ++q) ssum += mt[q*4 + tid];
    g_cwsp[b][s][tid] = ssum;
  }
}

// ------- Phase 5: WG (b, 32-col slice): reduce bwd, new read weights,
// ------- read-vector partials.
__global__ void __launch_bounds__(NT) k_ph5() {
  __shared__ __align__(16) float sm[144];
  const int w = (int)blockIdx.x, tid = threadIdx.x;
  const int b = w >> 4, s = w & 15, j0 = s * 32;
  float* Sr  = sm;        // 4
  float* rwt = sm + 16;   // 128
  if (tid < 4) {
    float ss = 0.f;
    #pragma unroll
    for (int q = 0; q < 16; ++q) ss += g_cwsp[b][q][tid];
    Sr[tid] = ss;
  }
  __syncthreads();
  if (tid < 128) {
    int jj = tid >> 2, r = tid & 3;
    int j = j0 + jj;
    float bw = 0.f;
    #pragma unroll
    for (int q = 0; q < 16; ++q) bw += g_bwdp[b][q][r][j];
    float fw = g_fwd[b][r][j];
    float cwv = g_e[b][r][j] / Sr[r];
    float rn = g_modes[b][r][0]*bw + g_modes[b][r][1]*fw + g_modes[b][r][2]*cwv;
    g_rw[b][r][j] = rn;
    rwt[r*32 + jj] = rn;
  }
  __syncthreads();
  {
    int r = tid >> 6, v = tid & 63;
    float acc = 0.f;
    #pragma unroll
    for (int jj = 0; jj < 32; ++jj) acc += rwt[r*32 + jj] * g_mem[b][j0 + jj][v];
    g_rvp[b][s][r][v] = acc;
  }
}

// ------- Phase 6: WG (b, 16-output slice): reduce read vectors, final y. -----
__global__ void __launch_bounds__(NT) k_ph6(P p, int t) {
  __shared__ __align__(16) float sm[1024];
  const int w = (int)blockIdx.x, tid = threadIdx.x;
  const int b = w >> 4, s = w & 15, o0 = s * 16;
  float* rv   = sm;         // 256
  float* outl = sm + 256;   // 512
  float* red  = sm + 768;   // 256
  {
    int r = tid >> 6, v = tid & 63;
    float acc = 0.f;
    #pragma unroll
    for (int q = 0; q < 16; ++q) acc += g_rvp[b][q][r][v];
    rv[r*64 + v] = acc;
    if (s == 0) g_lr[b][r*64 + v] = acc;   // last_read for next step
  }
  for (int k = tid; k < HH; k += NT) outl[k] = g_out[b][k];
  __syncthreads();
  {
    int oi = tid & 15, ks = tid >> 4;
    int o = o0 + oi;
    const float* wm = &p.W_mem[(size_t)o * 768];
    float acc = 0.f;
    for (int k = ks*48; k < ks*48 + 48; ++k) {
      float a = (k < HH) ? outl[k] : rv[k - HH];
      acc += a * wm[k];
    }
    red[oi*16 + ks] = acc;
  }
  __syncthreads();
  if (tid < 16) {
    int o = o0 + tid;
    float ss = 0.f;
    #pragma unroll
    for (int q = 0; q < 16; ++q) ss += red[tid*16 + q];
    p.y[((size_t)b*TT + t)*INP + o] = ss + p.b_mem[o];
  }
}

extern "C" void kernel_launch(void* const* d_in, const int* in_sizes, int n_in,
                              void* d_out, int out_size, void* d_ws, size_t ws_size,
                              hipStream_t stream) {
  (void)in_sizes; (void)n_in; (void)out_size; (void)d_ws; (void)ws_size;
  P p;
  p.x     = (const float*)d_in[0];
  p.W_ih  = (const float*)d_in[1];
  p.b_ih  = (const float*)d_in[2];
  p.W_hh  = (const float*)d_in[3];
  p.b_hh  = (const float*)d_in[4];
  p.W_out = (const float*)d_in[5];
  p.b_out = (const float*)d_in[6];
  p.W_int = (const float*)d_in[7];
  p.b_int = (const float*)d_in[8];
  p.W_mem = (const float*)d_in[9];
  p.b_mem = (const float*)d_in[10];
  p.y     = (float*)d_out;

  k_init<<<dim3(1024), dim3(NT), 0, stream>>>();
  for (int t = 0; t < TT; ++t) {
    const int pp = t & 1;
    k_ph1<<<dim3(NWG), dim3(NT), 0, stream>>>(p, t);
    k_ph2<<<dim3(NWG), dim3(NT), 0, stream>>>(p, t);
    k_ph3<<<dim3(NB),  dim3(512), 0, stream>>>(pp);
    k_ph4<<<dim3(NWG), dim3(NT), 0, stream>>>(pp);
    k_ph5<<<dim3(NWG), dim3(NT), 0, stream>>>();
    k_ph6<<<dim3(NWG), dim3(NT), 0, stream>>>(p, t);
  }
}